// Round 5
// baseline (524.807 us; speedup 1.0000x reference)
//
#include <hip/hip_runtime.h>

#define BB 4
#define LL 2048
#define DD 512
#define HH 8
#define NLAYER 2

typedef __attribute__((ext_vector_type(8))) short short8;
typedef __attribute__((ext_vector_type(4))) float floatx4;
typedef __attribute__((ext_vector_type(16))) float floatx16;

union U4S8 { uint4 u4; short8 s8; unsigned int u[4]; };

__device__ __forceinline__ unsigned short f2bf(float f) {
  unsigned int u = __float_as_uint(f);
  u += 0x7fffu + ((u >> 16) & 1u);
  return (unsigned short)(u >> 16);
}
__device__ __forceinline__ float bf2f(unsigned short s) {
  return __uint_as_float(((unsigned int)s) << 16);
}
__device__ __forceinline__ float bf2f_lo(unsigned int w) {
  return __uint_as_float(w << 16);
}
__device__ __forceinline__ float bf2f_hi(unsigned int w) {
  return __uint_as_float(w & 0xffff0000u);
}
// pack two fp32 -> bf16 pair, round-half-up
__device__ __forceinline__ unsigned int pack_bf16(float a0, float a1) {
  unsigned int u0 = __float_as_uint(a0) + 0x8000u;
  unsigned int u1 = __float_as_uint(a1) + 0x8000u;
  return __builtin_amdgcn_perm(u1, u0, 0x07060302u);
}
// truncating pack (1 op); bias cancels when lsum uses same truncated values
__device__ __forceinline__ unsigned int pack_bf16_trunc(float a0, float a1) {
  return __builtin_amdgcn_perm(__float_as_uint(a1), __float_as_uint(a0), 0x07060302u);
}
__device__ __forceinline__ float fast_exp2(float x) {
#if __has_builtin(__builtin_amdgcn_exp2f)
  return __builtin_amdgcn_exp2f(x);
#else
  return exp2f(x);
#endif
}
__device__ __forceinline__ float fast_exp(float x) {
  return fast_exp2(x * 1.442695040888963f);
}

// ---------------- batched weight transpose fp32 (512 x C) -> bf16 (C x 512) ----------------
struct TJob { const float* src; unsigned short* dst; int C; int il; };
struct TJobs { TJob j[12]; };

__global__ __launch_bounds__(256) void transpose_all_kernel(TJobs jobs) {
  TJob jb = jobs.j[blockIdx.z];
  int c0 = blockIdx.x * 32;
  if (c0 >= jb.C) return;
  const int R = 512;
  __shared__ float t[32][33];
  int r0 = blockIdx.y * 32;
#pragma unroll
  for (int i = 0; i < 4; i++) {
    int idx = threadIdx.x + i * 256;
    t[idx >> 5][idx & 31] = jb.src[(size_t)(r0 + (idx >> 5)) * jb.C + c0 + (idx & 31)];
  }
  __syncthreads();
#pragma unroll
  for (int i = 0; i < 4; i++) {
    int idx = threadIdx.x + i * 256;
    int cc = idx >> 5, rr = idx & 31;
    int c = c0 + cc;
    int orow = jb.il ? ((c < 512) ? 2 * c : 2 * (c - 512) + 1) : c;
    jb.dst[(size_t)orow * R + r0 + rr] = f2bf(t[rr][cc]);
  }
}

// ---------------- LayerNorm (D=512), block per row ----------------
__global__ __launch_bounds__(256) void ln_kernel(
    const float* __restrict__ x, const float* __restrict__ w, const float* __restrict__ b,
    unsigned short* __restrict__ outB, float* __restrict__ outF) {
  int row = blockIdx.x;
  const float* xr = x + (size_t)row * DD;
  int tid = threadIdx.x;
  float2 v = *(const float2*)(xr + tid * 2);
  float s = v.x + v.y;
  float ss = v.x * v.x + v.y * v.y;
#pragma unroll
  for (int off = 1; off < 64; off <<= 1) {
    s += __shfl_xor(s, off);
    ss += __shfl_xor(ss, off);
  }
  __shared__ float red[2][4];
  int wave = tid >> 6, lane = tid & 63;
  if (lane == 0) { red[0][wave] = s; red[1][wave] = ss; }
  __syncthreads();
  s = red[0][0] + red[0][1] + red[0][2] + red[0][3];
  ss = red[1][0] + red[1][1] + red[1][2] + red[1][3];
  float mu = s * (1.0f / DD);
  float var = ss * (1.0f / DD) - mu * mu;
  float inv = rsqrtf(var + 1e-5f);
#pragma unroll
  for (int j = 0; j < 2; j++) {
    int c = tid * 2 + j;
    float val = (((j == 0) ? v.x : v.y) - mu) * inv * w[c] + b[c];
    if (outB) outB[(size_t)row * DD + c] = f2bf(val);
    if (outF) outF[(size_t)row * DD + c] = val;
  }
}

// ---------------- GEMM: C[MxN] = A[MxK](bf16) * Bt[NxK](bf16)^T ----------------
// 128x128 tile, BK=32, global_load_lds(16B) with XOR-granule swizzle (m97-style).
__global__ __launch_bounds__(256) void gemm128_kernel(
    const unsigned short* __restrict__ A, const unsigned short* __restrict__ Bt,
    float* __restrict__ outF, unsigned short* __restrict__ outB,
    const float* __restrict__ res, int M, int N, int K) {
  __shared__ alignas(16) unsigned short As[128 * 32];
  __shared__ alignas(16) unsigned short Bs[128 * 32];
  const int tid = threadIdx.x;
  const int wave = tid >> 6, lane = tid & 63;
  const int l16 = lane & 15, quad = lane >> 4;
  const int wm = wave & 1, wn = wave >> 1;
  const int m0 = blockIdx.y * 128, n0 = blockIdx.x * 128;

  floatx4 acc[4][4];
#pragma unroll
  for (int i = 0; i < 4; i++)
#pragma unroll
    for (int j = 0; j < 4; j++)
#pragma unroll
      for (int r = 0; r < 4; r++) acc[i][j][r] = 0.f;

  const int grow = lane >> 2;
  const int gg = lane & 3;

  for (int kt = 0; kt < K; kt += 32) {
#pragma unroll
    for (int i = 0; i < 2; i++) {
      int rb = (wave * 2 + i) * 16;
      int row = rb + grow;
      int gsw = gg ^ (row & 3);
      const unsigned short* srcA = A + (size_t)(m0 + row) * K + kt + gsw * 8;
      const unsigned short* srcB = Bt + (size_t)(n0 + row) * K + kt + gsw * 8;
      __builtin_amdgcn_global_load_lds(
          (const __attribute__((address_space(1))) unsigned int*)srcA,
          (__attribute__((address_space(3))) unsigned int*)(As + rb * 32), 16, 0, 0);
      __builtin_amdgcn_global_load_lds(
          (const __attribute__((address_space(1))) unsigned int*)srcB,
          (__attribute__((address_space(3))) unsigned int*)(Bs + rb * 32), 16, 0, 0);
    }
    __syncthreads();
    short8 af[4], bf[4];
#pragma unroll
    for (int i = 0; i < 4; i++) {
      int rowa = wm * 64 + i * 16 + l16;
      af[i] = *(const short8*)&As[rowa * 32 + (quad ^ (rowa & 3)) * 8];
      int rowb = wn * 64 + i * 16 + l16;
      bf[i] = *(const short8*)&Bs[rowb * 32 + (quad ^ (rowb & 3)) * 8];
    }
#pragma unroll
    for (int i = 0; i < 4; i++)
#pragma unroll
      for (int j = 0; j < 4; j++)
        acc[i][j] = __builtin_amdgcn_mfma_f32_16x16x32_bf16(af[i], bf[j], acc[i][j], 0, 0, 0);
    __syncthreads();
  }
#pragma unroll
  for (int i = 0; i < 4; i++)
#pragma unroll
    for (int j = 0; j < 4; j++)
#pragma unroll
      for (int r = 0; r < 4; r++) {
        int row = m0 + wm * 64 + i * 16 + quad * 4 + r;
        int col = n0 + wn * 64 + j * 16 + l16;
        size_t idx = (size_t)row * N + col;
        float val = acc[i][j][r];
        if (res) val += res[idx];
        if (outF) outF[idx] = val;
        if (outB) outB[idx] = f2bf(val);
      }
}

// ---------------- GEMM 128x64 tile (for N=512 outputs: grid 512 -> 2 blocks/CU) ----------------
__global__ __launch_bounds__(256) void gemm64n_kernel(
    const unsigned short* __restrict__ A, const unsigned short* __restrict__ Bt,
    float* __restrict__ outF, const float* __restrict__ res, int M, int N, int K) {
  __shared__ alignas(16) unsigned short As[128 * 32];
  __shared__ alignas(16) unsigned short Bs[64 * 32];
  const int tid = threadIdx.x;
  const int wave = tid >> 6, lane = tid & 63;
  const int l16 = lane & 15, quad = lane >> 4;
  const int m0 = blockIdx.y * 128, n0 = blockIdx.x * 64;

  floatx4 acc[2][4];
#pragma unroll
  for (int i = 0; i < 2; i++)
#pragma unroll
    for (int j = 0; j < 4; j++)
#pragma unroll
      for (int r = 0; r < 4; r++) acc[i][j][r] = 0.f;

  const int grow = lane >> 2;
  const int gg = lane & 3;

  for (int kt = 0; kt < K; kt += 32) {
#pragma unroll
    for (int i = 0; i < 3; i++) {
      int id = wave * 3 + i;
      if (id < 8) {
        int rb = id * 16;
        int row = rb + grow;
        int gsw = gg ^ (row & 3);
        const unsigned short* srcA = A + (size_t)(m0 + row) * K + kt + gsw * 8;
        __builtin_amdgcn_global_load_lds(
            (const __attribute__((address_space(1))) unsigned int*)srcA,
            (__attribute__((address_space(3))) unsigned int*)(As + rb * 32), 16, 0, 0);
      } else {
        int rb = (id - 8) * 16;
        int row = rb + grow;
        int gsw = gg ^ (row & 3);
        const unsigned short* srcB = Bt + (size_t)(n0 + row) * K + kt + gsw * 8;
        __builtin_amdgcn_global_load_lds(
            (const __attribute__((address_space(1))) unsigned int*)srcB,
            (__attribute__((address_space(3))) unsigned int*)(Bs + rb * 32), 16, 0, 0);
      }
    }
    __syncthreads();
    short8 af[2], bfr[4];
#pragma unroll
    for (int i = 0; i < 2; i++) {
      int rowa = wave * 32 + i * 16 + l16;
      af[i] = *(const short8*)&As[rowa * 32 + (quad ^ (rowa & 3)) * 8];
    }
#pragma unroll
    for (int j = 0; j < 4; j++) {
      int rowb = j * 16 + l16;
      bfr[j] = *(const short8*)&Bs[rowb * 32 + (quad ^ (rowb & 3)) * 8];
    }
#pragma unroll
    for (int i = 0; i < 2; i++)
#pragma unroll
      for (int j = 0; j < 4; j++)
        acc[i][j] = __builtin_amdgcn_mfma_f32_16x16x32_bf16(af[i], bfr[j], acc[i][j], 0, 0, 0);
    __syncthreads();
  }
#pragma unroll
  for (int i = 0; i < 2; i++)
#pragma unroll
    for (int j = 0; j < 4; j++)
#pragma unroll
      for (int r = 0; r < 4; r++) {
        int row = m0 + wave * 32 + i * 16 + quad * 4 + r;
        int col = n0 + j * 16 + l16;
        size_t idx = (size_t)row * N + col;
        float val = acc[i][j][r];
        if (res) val += res[idx];
        outF[idx] = val;
      }
}

// ---------------- GEMM + fused SwiGLU epilogue ----------------
__global__ __launch_bounds__(256) void gemm_swiglu_kernel(
    const unsigned short* __restrict__ A, const unsigned short* __restrict__ Bt,
    unsigned short* __restrict__ gout, int M, int N, int K) {
  __shared__ alignas(16) unsigned short As[128 * 32];
  __shared__ alignas(16) unsigned short Bs[128 * 32];
  const int tid = threadIdx.x;
  const int wave = tid >> 6, lane = tid & 63;
  const int l16 = lane & 15, quad = lane >> 4;
  const int wm = wave & 1, wn = wave >> 1;
  const int m0 = blockIdx.y * 128, n0 = blockIdx.x * 128;
  floatx4 acc[4][4];
#pragma unroll
  for (int i = 0; i < 4; i++)
#pragma unroll
    for (int j = 0; j < 4; j++)
#pragma unroll
      for (int r = 0; r < 4; r++) acc[i][j][r] = 0.f;
  const int grow = lane >> 2;
  const int gg = lane & 3;
  for (int kt = 0; kt < K; kt += 32) {
#pragma unroll
    for (int i = 0; i < 2; i++) {
      int rb = (wave * 2 + i) * 16;
      int row = rb + grow;
      int gsw = gg ^ (row & 3);
      const unsigned short* srcA = A + (size_t)(m0 + row) * K + kt + gsw * 8;
      const unsigned short* srcB = Bt + (size_t)(n0 + row) * K + kt + gsw * 8;
      __builtin_amdgcn_global_load_lds(
          (const __attribute__((address_space(1))) unsigned int*)srcA,
          (__attribute__((address_space(3))) unsigned int*)(As + rb * 32), 16, 0, 0);
      __builtin_amdgcn_global_load_lds(
          (const __attribute__((address_space(1))) unsigned int*)srcB,
          (__attribute__((address_space(3))) unsigned int*)(Bs + rb * 32), 16, 0, 0);
    }
    __syncthreads();
    short8 af[4], bf[4];
#pragma unroll
    for (int i = 0; i < 4; i++) {
      int rowa = wm * 64 + i * 16 + l16;
      af[i] = *(const short8*)&As[rowa * 32 + (quad ^ (rowa & 3)) * 8];
      int rowb = wn * 64 + i * 16 + l16;
      bf[i] = *(const short8*)&Bs[rowb * 32 + (quad ^ (rowb & 3)) * 8];
    }
#pragma unroll
    for (int i = 0; i < 4; i++)
#pragma unroll
      for (int j = 0; j < 4; j++)
        acc[i][j] = __builtin_amdgcn_mfma_f32_16x16x32_bf16(af[i], bf[j], acc[i][j], 0, 0, 0);
    __syncthreads();
  }
  const int Nh = N >> 1;
#pragma unroll
  for (int i = 0; i < 4; i++)
#pragma unroll
    for (int j = 0; j < 4; j++)
#pragma unroll
      for (int r = 0; r < 4; r++) {
        float val = acc[i][j][r];
        float part = __shfl_xor(val, 1);
        float x1 = (l16 & 1) ? part : val;
        float x2 = (l16 & 1) ? val : part;
        float g = x1 / (1.f + fast_exp(-x1)) * x2;
        if (!(l16 & 1)) {
          int row = m0 + wm * 64 + i * 16 + quad * 4 + r;
          int gcol = (n0 + wn * 64 + j * 16 + l16) >> 1;
          gout[(size_t)row * Nh + gcol] = f2bf(g);
        }
      }
}

// ---------------- fused RoPE(q,k) + V-transpose ----------------
__global__ __launch_bounds__(256) void ropevt_kernel(
    unsigned short* __restrict__ qkv, const float* __restrict__ cosb,
    const float* __restrict__ sinb, unsigned short* __restrict__ vtp) {
  __shared__ unsigned short tt[64][72];
  int lt = blockIdx.x, bh = blockIdx.y;
  int b = bh >> 3, h = bh & 7;
  int tid = threadIdx.x;
  {
    int r = tid >> 2, d0 = (tid & 3) * 8;
    size_t trow = (size_t)(b * LL + lt * 64 + r);
    const float* cp = cosb + (size_t)(lt * 64 + r) * DD + d0;
    const float* sp = sinb + (size_t)(lt * 64 + r) * DD + d0;
    unsigned short* qp = qkv + trow * 1536 + h * 64 + d0;
    unsigned short* kp = qp + 512;
    float4 c1a = *(const float4*)cp, c1b = *(const float4*)(cp + 4);
    float4 c2a = *(const float4*)(cp + 32), c2b = *(const float4*)(cp + 36);
    float4 s1a = *(const float4*)sp, s1b = *(const float4*)(sp + 4);
    float4 s2a = *(const float4*)(sp + 32), s2b = *(const float4*)(sp + 36);
    float c1[8] = {c1a.x, c1a.y, c1a.z, c1a.w, c1b.x, c1b.y, c1b.z, c1b.w};
    float c2[8] = {c2a.x, c2a.y, c2a.z, c2a.w, c2b.x, c2b.y, c2b.z, c2b.w};
    float s1[8] = {s1a.x, s1a.y, s1a.z, s1a.w, s1b.x, s1b.y, s1b.z, s1b.w};
    float s2[8] = {s2a.x, s2a.y, s2a.z, s2a.w, s2b.x, s2b.y, s2b.z, s2b.w};
    U4S8 qlo, qhi, klo, khi;
    qlo.u4 = *(const uint4*)qp; qhi.u4 = *(const uint4*)(qp + 32);
    klo.u4 = *(const uint4*)kp; khi.u4 = *(const uint4*)(kp + 32);
    U4S8 qlo2, qhi2, klo2, khi2;
#pragma unroll
    for (int e = 0; e < 4; e++) {
      float q1a = bf2f((unsigned short)qlo.s8[2 * e]), q1b = bf2f((unsigned short)qlo.s8[2 * e + 1]);
      float q2a = bf2f((unsigned short)qhi.s8[2 * e]), q2b = bf2f((unsigned short)qhi.s8[2 * e + 1]);
      qlo2.u[e] = pack_bf16(q1a * c1[2 * e] - q2a * s1[2 * e], q1b * c1[2 * e + 1] - q2b * s1[2 * e + 1]);
      qhi2.u[e] = pack_bf16(q2a * c2[2 * e] + q1a * s2[2 * e], q2b * c2[2 * e + 1] + q1b * s2[2 * e + 1]);
      float k1a = bf2f((unsigned short)klo.s8[2 * e]), k1b = bf2f((unsigned short)klo.s8[2 * e + 1]);
      float k2a = bf2f((unsigned short)khi.s8[2 * e]), k2b = bf2f((unsigned short)khi.s8[2 * e + 1]);
      klo2.u[e] = pack_bf16(k1a * c1[2 * e] - k2a * s1[2 * e], k1b * c1[2 * e + 1] - k2b * s1[2 * e + 1]);
      khi2.u[e] = pack_bf16(k2a * c2[2 * e] + k1a * s2[2 * e], k2b * c2[2 * e + 1] + k1b * s2[2 * e + 1]);
    }
    *(uint4*)qp = qlo2.u4; *(uint4*)(qp + 32) = qhi2.u4;
    *(uint4*)kp = klo2.u4; *(uint4*)(kp + 32) = khi2.u4;
  }
  {
    int row = tid >> 2, c = (tid & 3) * 16;
    const unsigned short* src = qkv + (size_t)(b * LL + lt * 64 + row) * 1536 + 1024 + h * 64 + c;
    *(uint4*)&tt[row][c] = *(const uint4*)src;
    *(uint4*)&tt[row][c + 8] = *(const uint4*)(src + 8);
    __syncthreads();
    int d = tid >> 2, lg = tid & 3;
    unsigned short arr[16];
#pragma unroll
    for (int i = 0; i < 16; i++) {
      int j = (i + d) & 15;
      arr[j] = tt[lg * 16 + j][d];
    }
    unsigned int w[8];
#pragma unroll
    for (int g = 0; g < 8; g++)
      w[g] = (unsigned int)arr[2 * g] | ((unsigned int)arr[2 * g + 1] << 16);
    unsigned short* dst = vtp + (size_t)(bh * 64 + d) * 2048 + lt * 64 + lg * 16;
    *(uint4*)dst = make_uint4(w[0], w[1], w[2], w[3]);
    *(uint4*)(dst + 8) = make_uint4(w[4], w[5], w[6], w[7]);
  }
}

// ---------------- attention, split-K over keys: blockIdx.z = b*2 + kz ----------------
// Each block: 128 q (4 waves x 32q), keys [kz*1024, kz*1024+1024). Partial
// unnormalized O (bf16) -> opart[kz], partial L -> lpart. grid 1024 -> 4 blocks/CU.
__global__ __launch_bounds__(256, 4) void attn_kernel(
    const unsigned short* __restrict__ qkv, const unsigned short* __restrict__ vtp,
    const float* __restrict__ mask, unsigned short* __restrict__ opart0,
    unsigned short* __restrict__ opart1, float* __restrict__ lpart) {
  __shared__ alignas(16) unsigned short Ks[2][64][72];
  __shared__ alignas(16) unsigned short Vs[2][64][72];
  const int tid = threadIdx.x;
  const int wave = tid >> 6, lane = tid & 63;
  const int l5 = lane & 31, b5 = lane >> 5;
  const int b = blockIdx.z >> 1, kz = blockIdx.z & 1;
  const int h = blockIdx.y;
  const int q0 = blockIdx.x * 128 + wave * 32;
  const int bh = b * 8 + h;
  const int kstart = kz << 10;
  const float QSCALE = 0.125f * 1.442695040888963f;

  short8 qf[4];
  {
    const unsigned short* qp = qkv + (size_t)(b * LL + q0 + l5) * 1536 + h * 64 + b5 * 8;
#pragma unroll
    for (int t = 0; t < 4; t++) {
      U4S8 u;
      u.u4 = *(const uint4*)(qp + t * 16);
      short8 qs;
#pragma unroll
      for (int e = 0; e < 8; e++)
        qs[e] = (short)f2bf(bf2f((unsigned short)u.s8[e]) * QSCALE);
      qf[t] = qs;
    }
  }
  short8 bones = {0, 0, 0, 0, 0, 0, 0, 0};
  if (b5 == 0) bones[0] = (short)0x3F80;
  short8 onesA;
#pragma unroll
  for (int e = 0; e < 8; e++) onesA[e] = (short)0x3F80;

  floatx16 O[2], Lacc;
#pragma unroll
  for (int a = 0; a < 2; a++)
#pragma unroll
    for (int r = 0; r < 16; r++) O[a][r] = 0.f;
#pragma unroll
  for (int r = 0; r < 16; r++) Lacc[r] = 0.f;

  const int srow = tid >> 2, sc = (tid & 3) * 16;
  const unsigned short* kbase = qkv + (size_t)(b * LL + kstart + srow) * 1536 + 512 + h * 64 + sc;
  const unsigned short* vbase = vtp + (size_t)(bh * 64 + srow) * 2048 + kstart + sc;

  uint4 kr0 = *(const uint4*)kbase;
  uint4 kr1 = *(const uint4*)(kbase + 8);
  uint4 vr0 = *(const uint4*)vbase;
  uint4 vr1 = *(const uint4*)(vbase + 8);

  for (int tl = 0, it = 0; tl < 1024; tl += 64, it++) {
    const int buf = it & 1;
    *(uint4*)&Ks[buf][srow][sc] = kr0;
    *(uint4*)&Ks[buf][srow][sc + 8] = kr1;
    *(uint4*)&Vs[buf][srow][sc] = vr0;
    *(uint4*)&Vs[buf][srow][sc + 8] = vr1;
    __syncthreads();
    if (tl + 64 < 1024) {
      const unsigned short* kn = kbase + (size_t)(tl + 64) * 1536;
      const unsigned short* vn = vbase + tl + 64;
      kr0 = *(const uint4*)kn;
      kr1 = *(const uint4*)(kn + 8);
      vr0 = *(const uint4*)vn;
      vr1 = *(const uint4*)(vn + 8);
    }
    float mk0 = mask[b * LL + kstart + tl + l5];
    float mk1 = mask[b * LL + kstart + tl + 32 + l5];
    short8 kf[2][4];
#pragma unroll
    for (int ms = 0; ms < 2; ms++)
#pragma unroll
      for (int t = 0; t < 4; t++)
        kf[ms][t] = *(const short8*)&Ks[buf][ms * 32 + l5][t * 16 + b5 * 8];

    floatx16 s0, s1;
#pragma unroll
    for (int r = 0; r < 16; r++) { s0[r] = 0.f; s1[r] = 0.f; }
#pragma unroll
    for (int t = 0; t < 4; t++) {
      s0 = __builtin_amdgcn_mfma_f32_32x32x16_bf16(kf[0][t], qf[t], s0, 0, 0, 0);
      s1 = __builtin_amdgcn_mfma_f32_32x32x16_bf16(kf[1][t], qf[t], s1, 0, 0, 0);
    }
    // mask fast-path: skip the 2 mask-MFMAs when the whole tile's mask is 0
    if (__any(mk0 != 0.0f || mk1 != 0.0f)) {
      short8 am0 = {0, 0, 0, 0, 0, 0, 0, 0}, am1 = {0, 0, 0, 0, 0, 0, 0, 0};
      if (b5 == 0) {
        am0[0] = (short)f2bf(1.442695040888963f * mk0);
        am1[0] = (short)f2bf(1.442695040888963f * mk1);
      }
      s0 = __builtin_amdgcn_mfma_f32_32x32x16_bf16(am0, bones, s0, 0, 0, 0);
      s1 = __builtin_amdgcn_mfma_f32_32x32x16_bf16(am1, bones, s1, 0, 0, 0);
    }

    unsigned int pk[2][8];
#pragma unroll
    for (int i = 0; i < 8; i++) {
      pk[0][i] = pack_bf16_trunc(fast_exp2(s0[2 * i]), fast_exp2(s0[2 * i + 1]));
      pk[1][i] = pack_bf16_trunc(fast_exp2(s1[2 * i]), fast_exp2(s1[2 * i + 1]));
    }
#pragma unroll
    for (int ms = 0; ms < 2; ms++) {
#pragma unroll
      for (int kp = 0; kp < 2; kp++) {
        unsigned int se0 = b5 ? pk[ms][4 * kp] : pk[ms][4 * kp + 2];
        unsigned int se1 = b5 ? pk[ms][4 * kp + 1] : pk[ms][4 * kp + 3];
        unsigned int w0 = (unsigned int)__shfl_xor((int)se0, 32);
        unsigned int w1 = (unsigned int)__shfl_xor((int)se1, 32);
        U4S8 u;
        u.u[0] = b5 ? w0 : pk[ms][4 * kp];
        u.u[1] = b5 ? w1 : pk[ms][4 * kp + 1];
        u.u[2] = b5 ? pk[ms][4 * kp + 2] : w0;
        u.u[3] = b5 ? pk[ms][4 * kp + 3] : w1;
        short8 pb = u.s8;
        const int kst = ms * 2 + kp;
        short8 v0 = *(const short8*)&Vs[buf][l5][kst * 16 + b5 * 8];
        short8 v1 = *(const short8*)&Vs[buf][32 + l5][kst * 16 + b5 * 8];
        O[0] = __builtin_amdgcn_mfma_f32_32x32x16_bf16(v0, pb, O[0], 0, 0, 0);
        O[1] = __builtin_amdgcn_mfma_f32_32x32x16_bf16(v1, pb, O[1], 0, 0, 0);
        Lacc = __builtin_amdgcn_mfma_f32_32x32x16_bf16(onesA, pb, Lacc, 0, 0, 0);
      }
    }
  }
  int qrow = q0 + l5;
  unsigned short* op = (kz ? opart1 : opart0) + (size_t)(b * LL + qrow) * 512 + h * 64;
#pragma unroll
  for (int ds = 0; ds < 2; ds++) {
#pragma unroll
    for (int g = 0; g < 4; g++) {
      uint2 w;
      w.x = pack_bf16(O[ds][4 * g], O[ds][4 * g + 1]);
      w.y = pack_bf16(O[ds][4 * g + 2], O[ds][4 * g + 3]);
      *(uint2*)(op + ds * 32 + 8 * g + 4 * b5) = w;
    }
  }
  if (b5 == 0) lpart[(size_t)(kz * 32 + bh) * 2048 + qrow] = Lacc[0];
}

// ---------------- combine: ctx = (O0 + O1) / (L0 + L1) ----------------
// NOTE: `out` aliases o1 element-for-element (read-before-write per thread) — no __restrict__.
__global__ __launch_bounds__(256) void attn_combine_kernel(
    const unsigned short* o0, const unsigned short* o1,
    const float* __restrict__ lp, unsigned short* out) {
  int gtid = blockIdx.x * 256 + threadIdx.x;  // 8192*512/4 threads
  int row = gtid >> 7;
  int c = (gtid & 127) * 4;
  int b = row >> 11, q = row & 2047, h = c >> 6;
  int bh = b * 8 + h;
  float L = lp[(size_t)bh * 2048 + q] + lp[(size_t)(32 + bh) * 2048 + q];
  float inv = 1.0f / L;
  uint2 a = *(const uint2*)&o0[(size_t)row * 512 + c];
  uint2 bb = *(const uint2*)&o1[(size_t)row * 512 + c];
  float e0 = (bf2f_lo(a.x) + bf2f_lo(bb.x)) * inv;
  float e1 = (bf2f_hi(a.x) + bf2f_hi(bb.x)) * inv;
  float e2 = (bf2f_lo(a.y) + bf2f_lo(bb.y)) * inv;
  float e3 = (bf2f_hi(a.y) + bf2f_hi(bb.y)) * inv;
  uint2 w;
  w.x = pack_bf16(e0, e1);
  w.y = pack_bf16(e2, e3);
  *(uint2*)&out[(size_t)row * 512 + c] = w;
}

extern "C" void kernel_launch(void* const* d_in, const int* in_sizes, int n_in,
                              void* d_out, int out_size, void* d_ws, size_t ws_size,
                              hipStream_t stream) {
  const float* x_in = (const float*)d_in[0];
  const float* pcos = (const float*)d_in[1];
  const float* psin = (const float*)d_in[2];
  const float* amask = (const float*)d_in[3];
  const float* Wq = (const float*)d_in[4];
  const float* Wk = (const float*)d_in[5];
  const float* Wv = (const float*)d_in[6];
  const float* Wo = (const float*)d_in[7];
  const float* W1 = (const float*)d_in[8];
  const float* W2 = (const float*)d_in[9];
  const float* ln1w = (const float*)d_in[10];
  const float* ln1b = (const float*)d_in[11];
  const float* ln2w = (const float*)d_in[12];
  const float* ln2b = (const float*)d_in[13];
  const float* lnfw = (const float*)d_in[14];
  const float* lnfb = (const float*)d_in[15];

  const int M = BB * LL;  // 8192
  char* p = (char*)d_ws;
  float* x_ws = (float*)p;                  p += (size_t)M * DD * 4;
  unsigned short* xn = (unsigned short*)p;  p += (size_t)M * DD * 2;
  unsigned short* qkv = (unsigned short*)p; p += (size_t)M * 1536 * 2;
  unsigned short* vtb = (unsigned short*)p; p += (size_t)M * DD * 2;
  unsigned short* cb = (unsigned short*)p;  p += (size_t)M * DD * 2;
  float* lpart = (float*)p;                 p += (size_t)64 * 2048 * 4;
  unsigned short* wts = (unsigned short*)p;
  unsigned short* gb = vtb;   // vtb dead after attn; reused for SwiGLU output
  unsigned short* op0 = xn;   // xn dead after QKV gemm; attn partial kz=0
  unsigned short* op1 = cb;   // attn partial kz=1; combine writes ctx back into cb

  const size_t LW = 786432 + 262144 + 524288 + 262144;
  TJobs jobs;
  for (int i = 0; i < NLAYER; i++) {
    unsigned short* wl = wts + i * LW;
    jobs.j[i * 6 + 0] = {Wq + (size_t)i * 262144, wl + 0, 512, 0};
    jobs.j[i * 6 + 1] = {Wk + (size_t)i * 262144, wl + 262144, 512, 0};
    jobs.j[i * 6 + 2] = {Wv + (size_t)i * 262144, wl + 524288, 512, 0};
    jobs.j[i * 6 + 3] = {Wo + (size_t)i * 262144, wl + 786432, 512, 0};
    jobs.j[i * 6 + 4] = {W1 + (size_t)i * 524288, wl + 1048576, 1024, 1};
    jobs.j[i * 6 + 5] = {W2 + (size_t)i * 262144, wl + 1572864, 512, 0};
  }
  transpose_all_kernel<<<dim3(32, 16, 12), 256, 0, stream>>>(jobs);

  for (int i = 0; i < NLAYER; i++) {
    unsigned short* wl = wts + i * LW;
    const float* xin = (i == 0) ? x_in : x_ws;
    ln_kernel<<<M, 256, 0, stream>>>(xin, ln1w + i * DD, ln1b + i * DD, xn, nullptr);
    gemm128_kernel<<<dim3(12, 64), 256, 0, stream>>>(xn, wl + 0, nullptr, qkv, nullptr, M, 1536, 512);
    ropevt_kernel<<<dim3(32, 32), 256, 0, stream>>>(qkv, pcos, psin, vtb);
    attn_kernel<<<dim3(LL / 128, HH, BB * 2), 256, 0, stream>>>(qkv, vtb, amask, op0, op1, lpart);
    attn_combine_kernel<<<(M * DD / 4) / 256, 256, 0, stream>>>(op0, op1, lpart, cb);
    gemm64n_kernel<<<dim3(8, 64), 256, 0, stream>>>(cb, wl + 786432, x_ws, xin, M, 512, 512);
    ln_kernel<<<M, 256, 0, stream>>>(x_ws, ln2w + i * DD, ln2b + i * DD, xn, nullptr);
    gemm_swiglu_kernel<<<dim3(8, 64), 256, 0, stream>>>(xn, wl + 1048576, gb, M, 1024, 512);
    gemm64n_kernel<<<dim3(8, 64), 256, 0, stream>>>(gb, wl + 1572864, x_ws, x_ws, M, 512, 512);
  }
  ln_kernel<<<M, 256, 0, stream>>>(x_ws, lnfw, lnfb, nullptr, (float*)d_out);
}

// Round 6
// 477.552 us; speedup vs baseline: 1.0990x; 1.0990x over previous
//
#include <hip/hip_runtime.h>

#define BB 4
#define LL 2048
#define DD 512
#define HH 8
#define NLAYER 2

typedef __attribute__((ext_vector_type(8))) short short8;
typedef __attribute__((ext_vector_type(4))) float floatx4;
typedef __attribute__((ext_vector_type(16))) float floatx16;

union U4S8 { uint4 u4; short8 s8; unsigned int u[4]; };

__device__ __forceinline__ unsigned short f2bf(float f) {
  unsigned int u = __float_as_uint(f);
  u += 0x7fffu + ((u >> 16) & 1u);
  return (unsigned short)(u >> 16);
}
__device__ __forceinline__ float bf2f(unsigned short s) {
  return __uint_as_float(((unsigned int)s) << 16);
}
// pack two fp32 -> bf16 pair, round-half-up
__device__ __forceinline__ unsigned int pack_bf16(float a0, float a1) {
  unsigned int u0 = __float_as_uint(a0) + 0x8000u;
  unsigned int u1 = __float_as_uint(a1) + 0x8000u;
  return __builtin_amdgcn_perm(u1, u0, 0x07060302u);
}
// truncating pack (1 op); bias cancels when lsum uses same truncated values
__device__ __forceinline__ unsigned int pack_bf16_trunc(float a0, float a1) {
  return __builtin_amdgcn_perm(__float_as_uint(a1), __float_as_uint(a0), 0x07060302u);
}
__device__ __forceinline__ float fast_exp2(float x) {
#if __has_builtin(__builtin_amdgcn_exp2f)
  return __builtin_amdgcn_exp2f(x);
#else
  return exp2f(x);
#endif
}
__device__ __forceinline__ float fast_exp(float x) {
  return fast_exp2(x * 1.442695040888963f);
}

// ---------------- batched weight transpose fp32 (512 x C) -> bf16 (C x 512) ----------------
struct TJob { const float* src; unsigned short* dst; int C; int il; };
struct TJobs { TJob j[12]; };

__global__ __launch_bounds__(256) void transpose_all_kernel(TJobs jobs) {
  TJob jb = jobs.j[blockIdx.z];
  int c0 = blockIdx.x * 32;
  if (c0 >= jb.C) return;
  const int R = 512;
  __shared__ float t[32][33];
  int r0 = blockIdx.y * 32;
#pragma unroll
  for (int i = 0; i < 4; i++) {
    int idx = threadIdx.x + i * 256;
    t[idx >> 5][idx & 31] = jb.src[(size_t)(r0 + (idx >> 5)) * jb.C + c0 + (idx & 31)];
  }
  __syncthreads();
#pragma unroll
  for (int i = 0; i < 4; i++) {
    int idx = threadIdx.x + i * 256;
    int cc = idx >> 5, rr = idx & 31;
    int c = c0 + cc;
    int orow = jb.il ? ((c < 512) ? 2 * c : 2 * (c - 512) + 1) : c;
    jb.dst[(size_t)orow * R + r0 + rr] = f2bf(t[rr][cc]);
  }
}

// ---------------- LayerNorm (D=512), block per row ----------------
__global__ __launch_bounds__(256) void ln_kernel(
    const float* __restrict__ x, const float* __restrict__ w, const float* __restrict__ b,
    unsigned short* __restrict__ outB, float* __restrict__ outF) {
  int row = blockIdx.x;
  const float* xr = x + (size_t)row * DD;
  int tid = threadIdx.x;
  float2 v = *(const float2*)(xr + tid * 2);
  float s = v.x + v.y;
  float ss = v.x * v.x + v.y * v.y;
#pragma unroll
  for (int off = 1; off < 64; off <<= 1) {
    s += __shfl_xor(s, off);
    ss += __shfl_xor(ss, off);
  }
  __shared__ float red[2][4];
  int wave = tid >> 6, lane = tid & 63;
  if (lane == 0) { red[0][wave] = s; red[1][wave] = ss; }
  __syncthreads();
  s = red[0][0] + red[0][1] + red[0][2] + red[0][3];
  ss = red[1][0] + red[1][1] + red[1][2] + red[1][3];
  float mu = s * (1.0f / DD);
  float var = ss * (1.0f / DD) - mu * mu;
  float inv = rsqrtf(var + 1e-5f);
#pragma unroll
  for (int j = 0; j < 2; j++) {
    int c = tid * 2 + j;
    float val = (((j == 0) ? v.x : v.y) - mu) * inv * w[c] + b[c];
    if (outB) outB[(size_t)row * DD + c] = f2bf(val);
    if (outF) outF[(size_t)row * DD + c] = val;
  }
}

// ---------------- GEMM: C[MxN] = A[MxK](bf16) * Bt[NxK](bf16)^T ----------------
// 128x128 tile, BK=32, global_load_lds(16B) with XOR-granule swizzle (m97-style).
// If vtp != null, tiles with n0 >= 1024 (the V columns of the QKV gemm) are
// written TRANSPOSED to vtp[bh*64+d][seq] instead of outB.
__global__ __launch_bounds__(256) void gemm128_kernel(
    const unsigned short* __restrict__ A, const unsigned short* __restrict__ Bt,
    float* __restrict__ outF, unsigned short* __restrict__ outB,
    const float* __restrict__ res, int M, int N, int K,
    unsigned short* __restrict__ vtp) {
  __shared__ alignas(16) unsigned short As[128 * 32];
  __shared__ alignas(16) unsigned short Bs[128 * 32];
  const int tid = threadIdx.x;
  const int wave = tid >> 6, lane = tid & 63;
  const int l16 = lane & 15, quad = lane >> 4;
  const int wm = wave & 1, wn = wave >> 1;
  const int m0 = blockIdx.y * 128, n0 = blockIdx.x * 128;

  floatx4 acc[4][4];
#pragma unroll
  for (int i = 0; i < 4; i++)
#pragma unroll
    for (int j = 0; j < 4; j++)
#pragma unroll
      for (int r = 0; r < 4; r++) acc[i][j][r] = 0.f;

  const int grow = lane >> 2;
  const int gg = lane & 3;

  for (int kt = 0; kt < K; kt += 32) {
#pragma unroll
    for (int i = 0; i < 2; i++) {
      int rb = (wave * 2 + i) * 16;
      int row = rb + grow;
      int gsw = gg ^ (row & 3);
      const unsigned short* srcA = A + (size_t)(m0 + row) * K + kt + gsw * 8;
      const unsigned short* srcB = Bt + (size_t)(n0 + row) * K + kt + gsw * 8;
      __builtin_amdgcn_global_load_lds(
          (const __attribute__((address_space(1))) unsigned int*)srcA,
          (__attribute__((address_space(3))) unsigned int*)(As + rb * 32), 16, 0, 0);
      __builtin_amdgcn_global_load_lds(
          (const __attribute__((address_space(1))) unsigned int*)srcB,
          (__attribute__((address_space(3))) unsigned int*)(Bs + rb * 32), 16, 0, 0);
    }
    __syncthreads();
    short8 af[4], bf[4];
#pragma unroll
    for (int i = 0; i < 4; i++) {
      int rowa = wm * 64 + i * 16 + l16;
      af[i] = *(const short8*)&As[rowa * 32 + (quad ^ (rowa & 3)) * 8];
      int rowb = wn * 64 + i * 16 + l16;
      bf[i] = *(const short8*)&Bs[rowb * 32 + (quad ^ (rowb & 3)) * 8];
    }
#pragma unroll
    for (int i = 0; i < 4; i++)
#pragma unroll
      for (int j = 0; j < 4; j++)
        acc[i][j] = __builtin_amdgcn_mfma_f32_16x16x32_bf16(af[i], bf[j], acc[i][j], 0, 0, 0);
    __syncthreads();
  }
  if (vtp && n0 >= 1024) {
    // transposed V store: 4 consecutive seq rows (r) per 8B chunk, same d
#pragma unroll
    for (int i = 0; i < 4; i++)
#pragma unroll
      for (int j = 0; j < 4; j++) {
        int cg = (n0 - 1024) + wn * 64 + j * 16 + l16;  // 0..511
        int hh = cg >> 6, dd = cg & 63;
        int seq0 = m0 + wm * 64 + i * 16 + quad * 4;
        int bI = seq0 >> 11, ls = seq0 & 2047;
        unsigned short* dst = vtp + ((size_t)(bI * 8 + hh) * 64 + dd) * 2048 + ls;
        uint2 w;
        w.x = pack_bf16(acc[i][j][0], acc[i][j][1]);
        w.y = pack_bf16(acc[i][j][2], acc[i][j][3]);
        *(uint2*)dst = w;
      }
    return;
  }
#pragma unroll
  for (int i = 0; i < 4; i++)
#pragma unroll
    for (int j = 0; j < 4; j++)
#pragma unroll
      for (int r = 0; r < 4; r++) {
        int row = m0 + wm * 64 + i * 16 + quad * 4 + r;
        int col = n0 + wn * 64 + j * 16 + l16;
        size_t idx = (size_t)row * N + col;
        float val = acc[i][j][r];
        if (res) val += res[idx];
        if (outF) outF[idx] = val;
        if (outB) outB[idx] = f2bf(val);
      }
}

// ---------------- GEMM 128x64 tile (for N=512 outputs: grid 512 -> 2 blocks/CU) ----------------
__global__ __launch_bounds__(256) void gemm64n_kernel(
    const unsigned short* __restrict__ A, const unsigned short* __restrict__ Bt,
    float* __restrict__ outF, const float* __restrict__ res, int M, int N, int K) {
  __shared__ alignas(16) unsigned short As[128 * 32];
  __shared__ alignas(16) unsigned short Bs[64 * 32];
  const int tid = threadIdx.x;
  const int wave = tid >> 6, lane = tid & 63;
  const int l16 = lane & 15, quad = lane >> 4;
  const int m0 = blockIdx.y * 128, n0 = blockIdx.x * 64;

  floatx4 acc[2][4];
#pragma unroll
  for (int i = 0; i < 2; i++)
#pragma unroll
    for (int j = 0; j < 4; j++)
#pragma unroll
      for (int r = 0; r < 4; r++) acc[i][j][r] = 0.f;

  const int grow = lane >> 2;
  const int gg = lane & 3;

  for (int kt = 0; kt < K; kt += 32) {
#pragma unroll
    for (int i = 0; i < 3; i++) {
      int id = wave * 3 + i;
      if (id < 8) {
        int rb = id * 16;
        int row = rb + grow;
        int gsw = gg ^ (row & 3);
        const unsigned short* srcA = A + (size_t)(m0 + row) * K + kt + gsw * 8;
        __builtin_amdgcn_global_load_lds(
            (const __attribute__((address_space(1))) unsigned int*)srcA,
            (__attribute__((address_space(3))) unsigned int*)(As + rb * 32), 16, 0, 0);
      } else {
        int rb = (id - 8) * 16;
        int row = rb + grow;
        int gsw = gg ^ (row & 3);
        const unsigned short* srcB = Bt + (size_t)(n0 + row) * K + kt + gsw * 8;
        __builtin_amdgcn_global_load_lds(
            (const __attribute__((address_space(1))) unsigned int*)srcB,
            (__attribute__((address_space(3))) unsigned int*)(Bs + rb * 32), 16, 0, 0);
      }
    }
    __syncthreads();
    short8 af[2], bfr[4];
#pragma unroll
    for (int i = 0; i < 2; i++) {
      int rowa = wave * 32 + i * 16 + l16;
      af[i] = *(const short8*)&As[rowa * 32 + (quad ^ (rowa & 3)) * 8];
    }
#pragma unroll
    for (int j = 0; j < 4; j++) {
      int rowb = j * 16 + l16;
      bfr[j] = *(const short8*)&Bs[rowb * 32 + (quad ^ (rowb & 3)) * 8];
    }
#pragma unroll
    for (int i = 0; i < 2; i++)
#pragma unroll
      for (int j = 0; j < 4; j++)
        acc[i][j] = __builtin_amdgcn_mfma_f32_16x16x32_bf16(af[i], bfr[j], acc[i][j], 0, 0, 0);
    __syncthreads();
  }
#pragma unroll
  for (int i = 0; i < 2; i++)
#pragma unroll
    for (int j = 0; j < 4; j++)
#pragma unroll
      for (int r = 0; r < 4; r++) {
        int row = m0 + wave * 32 + i * 16 + quad * 4 + r;
        int col = n0 + j * 16 + l16;
        size_t idx = (size_t)row * N + col;
        float val = acc[i][j][r];
        if (res) val += res[idx];
        outF[idx] = val;
      }
}

// ---------------- GEMM + fused SwiGLU epilogue ----------------
__global__ __launch_bounds__(256) void gemm_swiglu_kernel(
    const unsigned short* __restrict__ A, const unsigned short* __restrict__ Bt,
    unsigned short* __restrict__ gout, int M, int N, int K) {
  __shared__ alignas(16) unsigned short As[128 * 32];
  __shared__ alignas(16) unsigned short Bs[128 * 32];
  const int tid = threadIdx.x;
  const int wave = tid >> 6, lane = tid & 63;
  const int l16 = lane & 15, quad = lane >> 4;
  const int wm = wave & 1, wn = wave >> 1;
  const int m0 = blockIdx.y * 128, n0 = blockIdx.x * 128;
  floatx4 acc[4][4];
#pragma unroll
  for (int i = 0; i < 4; i++)
#pragma unroll
    for (int j = 0; j < 4; j++)
#pragma unroll
      for (int r = 0; r < 4; r++) acc[i][j][r] = 0.f;
  const int grow = lane >> 2;
  const int gg = lane & 3;
  for (int kt = 0; kt < K; kt += 32) {
#pragma unroll
    for (int i = 0; i < 2; i++) {
      int rb = (wave * 2 + i) * 16;
      int row = rb + grow;
      int gsw = gg ^ (row & 3);
      const unsigned short* srcA = A + (size_t)(m0 + row) * K + kt + gsw * 8;
      const unsigned short* srcB = Bt + (size_t)(n0 + row) * K + kt + gsw * 8;
      __builtin_amdgcn_global_load_lds(
          (const __attribute__((address_space(1))) unsigned int*)srcA,
          (__attribute__((address_space(3))) unsigned int*)(As + rb * 32), 16, 0, 0);
      __builtin_amdgcn_global_load_lds(
          (const __attribute__((address_space(1))) unsigned int*)srcB,
          (__attribute__((address_space(3))) unsigned int*)(Bs + rb * 32), 16, 0, 0);
    }
    __syncthreads();
    short8 af[4], bf[4];
#pragma unroll
    for (int i = 0; i < 4; i++) {
      int rowa = wm * 64 + i * 16 + l16;
      af[i] = *(const short8*)&As[rowa * 32 + (quad ^ (rowa & 3)) * 8];
      int rowb = wn * 64 + i * 16 + l16;
      bf[i] = *(const short8*)&Bs[rowb * 32 + (quad ^ (rowb & 3)) * 8];
    }
#pragma unroll
    for (int i = 0; i < 4; i++)
#pragma unroll
      for (int j = 0; j < 4; j++)
        acc[i][j] = __builtin_amdgcn_mfma_f32_16x16x32_bf16(af[i], bf[j], acc[i][j], 0, 0, 0);
    __syncthreads();
  }
  const int Nh = N >> 1;
#pragma unroll
  for (int i = 0; i < 4; i++)
#pragma unroll
    for (int j = 0; j < 4; j++)
#pragma unroll
      for (int r = 0; r < 4; r++) {
        float val = acc[i][j][r];
        float part = __shfl_xor(val, 1);
        float x1 = (l16 & 1) ? part : val;
        float x2 = (l16 & 1) ? val : part;
        float g = x1 / (1.f + fast_exp(-x1)) * x2;
        if (!(l16 & 1)) {
          int row = m0 + wm * 64 + i * 16 + quad * 4 + r;
          int gcol = (n0 + wn * 64 + j * 16 + l16) >> 1;
          gout[(size_t)row * Nh + gcol] = f2bf(g);
        }
      }
}

// ---------------- RoPE on q,k (V handled by gemm epilogue) ----------------
__global__ __launch_bounds__(256) void rope_kernel(
    unsigned short* __restrict__ qkv, const float* __restrict__ cosb,
    const float* __restrict__ sinb) {
  int lt = blockIdx.x, bh = blockIdx.y;
  int b = bh >> 3, h = bh & 7;
  int tid = threadIdx.x;
  int r = tid >> 2, d0 = (tid & 3) * 8;
  size_t trow = (size_t)(b * LL + lt * 64 + r);
  // cos/sin are b- and h-invariant: read the (b=0,h=0) slice (L2-shared)
  const float* cp = cosb + (size_t)(lt * 64 + r) * DD + d0;
  const float* sp = sinb + (size_t)(lt * 64 + r) * DD + d0;
  unsigned short* qp = qkv + trow * 1536 + h * 64 + d0;
  unsigned short* kp = qp + 512;
  float4 c1a = *(const float4*)cp, c1b = *(const float4*)(cp + 4);
  float4 c2a = *(const float4*)(cp + 32), c2b = *(const float4*)(cp + 36);
  float4 s1a = *(const float4*)sp, s1b = *(const float4*)(sp + 4);
  float4 s2a = *(const float4*)(sp + 32), s2b = *(const float4*)(sp + 36);
  float c1[8] = {c1a.x, c1a.y, c1a.z, c1a.w, c1b.x, c1b.y, c1b.z, c1b.w};
  float c2[8] = {c2a.x, c2a.y, c2a.z, c2a.w, c2b.x, c2b.y, c2b.z, c2b.w};
  float s1[8] = {s1a.x, s1a.y, s1a.z, s1a.w, s1b.x, s1b.y, s1b.z, s1b.w};
  float s2[8] = {s2a.x, s2a.y, s2a.z, s2a.w, s2b.x, s2b.y, s2b.z, s2b.w};
  U4S8 qlo, qhi, klo, khi;
  qlo.u4 = *(const uint4*)qp; qhi.u4 = *(const uint4*)(qp + 32);
  klo.u4 = *(const uint4*)kp; khi.u4 = *(const uint4*)(kp + 32);
  U4S8 qlo2, qhi2, klo2, khi2;
#pragma unroll
  for (int e = 0; e < 4; e++) {
    float q1a = bf2f((unsigned short)qlo.s8[2 * e]), q1b = bf2f((unsigned short)qlo.s8[2 * e + 1]);
    float q2a = bf2f((unsigned short)qhi.s8[2 * e]), q2b = bf2f((unsigned short)qhi.s8[2 * e + 1]);
    qlo2.u[e] = pack_bf16(q1a * c1[2 * e] - q2a * s1[2 * e], q1b * c1[2 * e + 1] - q2b * s1[2 * e + 1]);
    qhi2.u[e] = pack_bf16(q2a * c2[2 * e] + q1a * s2[2 * e], q2b * c2[2 * e + 1] + q1b * s2[2 * e + 1]);
    float k1a = bf2f((unsigned short)klo.s8[2 * e]), k1b = bf2f((unsigned short)klo.s8[2 * e + 1]);
    float k2a = bf2f((unsigned short)khi.s8[2 * e]), k2b = bf2f((unsigned short)khi.s8[2 * e + 1]);
    klo2.u[e] = pack_bf16(k1a * c1[2 * e] - k2a * s1[2 * e], k1b * c1[2 * e + 1] - k2b * s1[2 * e + 1]);
    khi2.u[e] = pack_bf16(k2a * c2[2 * e] + k1a * s2[2 * e], k2b * c2[2 * e + 1] + k1b * s2[2 * e + 1]);
  }
  *(uint4*)qp = qlo2.u4; *(uint4*)(qp + 32) = qhi2.u4;
  *(uint4*)kp = klo2.u4; *(uint4*)(kp + 32) = khi2.u4;
}

// ---------------- attention: S^T = K Q^T via 32x32x16 MFMA ----------------
// Software-pipelined: QK(t) overlaps exp/pack/PV(t-1). Triple-buffered LDS
// (skew <= 1 iter: stores at t+1 hit buf (t+1)%3 != (t-1)%3 -> one barrier/iter).
__global__ __launch_bounds__(256, 2) void attn_kernel(
    const unsigned short* __restrict__ qkv, const unsigned short* __restrict__ vtp,
    const float* __restrict__ mask, unsigned short* __restrict__ ctx) {
  __shared__ alignas(16) unsigned short Ks[3][64][72];
  __shared__ alignas(16) unsigned short Vs[3][64][72];
  const int tid = threadIdx.x;
  const int wave = tid >> 6, lane = tid & 63;
  const int l5 = lane & 31, b5 = lane >> 5;
  const int b = blockIdx.z, h = blockIdx.y;
  const int q0 = blockIdx.x * 128 + wave * 32;
  const int bh = b * 8 + h;
  const float QSCALE = 0.125f * 1.442695040888963f;

  short8 qf[4];
  {
    const unsigned short* qp = qkv + (size_t)(b * LL + q0 + l5) * 1536 + h * 64 + b5 * 8;
#pragma unroll
    for (int t = 0; t < 4; t++) {
      U4S8 u;
      u.u4 = *(const uint4*)(qp + t * 16);
      short8 qs;
#pragma unroll
      for (int e = 0; e < 8; e++)
        qs[e] = (short)f2bf(bf2f((unsigned short)u.s8[e]) * QSCALE);
      qf[t] = qs;
    }
  }
  short8 bones = {0, 0, 0, 0, 0, 0, 0, 0};
  if (b5 == 0) bones[0] = (short)0x3F80;
  short8 onesA;
#pragma unroll
  for (int e = 0; e < 8; e++) onesA[e] = (short)0x3F80;

  floatx16 O[2], Lacc;
#pragma unroll
  for (int a = 0; a < 2; a++)
#pragma unroll
    for (int r = 0; r < 16; r++) O[a][r] = 0.f;
#pragma unroll
  for (int r = 0; r < 16; r++) Lacc[r] = 0.f;

  const int srow = tid >> 2, sc = (tid & 3) * 16;
  const unsigned short* kbase = qkv + (size_t)(b * LL + srow) * 1536 + 512 + h * 64 + sc;
  const unsigned short* vbase = vtp + (size_t)(bh * 64 + srow) * 2048 + sc;

  uint4 kr0 = *(const uint4*)kbase;
  uint4 kr1 = *(const uint4*)(kbase + 8);
  uint4 vr0 = *(const uint4*)vbase;
  uint4 vr1 = *(const uint4*)(vbase + 8);

  // PV+lsum for S held in (a0,a1) against V buffer vb
  auto do_pv = [&](const floatx16& a0, const floatx16& a1, int vb) {
    unsigned int pk[2][8];
#pragma unroll
    for (int i = 0; i < 8; i++) {
      pk[0][i] = pack_bf16_trunc(fast_exp2(a0[2 * i]), fast_exp2(a0[2 * i + 1]));
      pk[1][i] = pack_bf16_trunc(fast_exp2(a1[2 * i]), fast_exp2(a1[2 * i + 1]));
    }
#pragma unroll
    for (int ms = 0; ms < 2; ms++) {
#pragma unroll
      for (int kp = 0; kp < 2; kp++) {
        unsigned int se0 = b5 ? pk[ms][4 * kp] : pk[ms][4 * kp + 2];
        unsigned int se1 = b5 ? pk[ms][4 * kp + 1] : pk[ms][4 * kp + 3];
        unsigned int w0 = (unsigned int)__shfl_xor((int)se0, 32);
        unsigned int w1 = (unsigned int)__shfl_xor((int)se1, 32);
        U4S8 u;
        u.u[0] = b5 ? w0 : pk[ms][4 * kp];
        u.u[1] = b5 ? w1 : pk[ms][4 * kp + 1];
        u.u[2] = b5 ? pk[ms][4 * kp + 2] : w0;
        u.u[3] = b5 ? pk[ms][4 * kp + 3] : w1;
        short8 pb = u.s8;
        const int kst = ms * 2 + kp;
        short8 v0 = *(const short8*)&Vs[vb][l5][kst * 16 + b5 * 8];
        short8 v1 = *(const short8*)&Vs[vb][32 + l5][kst * 16 + b5 * 8];
        O[0] = __builtin_amdgcn_mfma_f32_32x32x16_bf16(v0, pb, O[0], 0, 0, 0);
        O[1] = __builtin_amdgcn_mfma_f32_32x32x16_bf16(v1, pb, O[1], 0, 0, 0);
        Lacc = __builtin_amdgcn_mfma_f32_32x32x16_bf16(onesA, pb, Lacc, 0, 0, 0);
      }
    }
  };

  floatx16 sp0, sp1;
  int buf = 0, pbuf = 0;
  for (int it = 0; it < 32; it++) {
    *(uint4*)&Ks[buf][srow][sc] = kr0;
    *(uint4*)&Ks[buf][srow][sc + 8] = kr1;
    *(uint4*)&Vs[buf][srow][sc] = vr0;
    *(uint4*)&Vs[buf][srow][sc + 8] = vr1;
    __syncthreads();
    if (it < 31) {
      const unsigned short* kn = kbase + (size_t)((it + 1) * 64) * 1536;
      const unsigned short* vn = vbase + (it + 1) * 64;
      kr0 = *(const uint4*)kn;
      kr1 = *(const uint4*)(kn + 8);
      vr0 = *(const uint4*)vn;
      vr1 = *(const uint4*)(vn + 8);
    }
    int t0 = it * 64;
    float mk0 = mask[b * LL + t0 + l5];
    float mk1 = mask[b * LL + t0 + 32 + l5];
    short8 kf[2][4];
#pragma unroll
    for (int ms = 0; ms < 2; ms++)
#pragma unroll
      for (int t = 0; t < 4; t++)
        kf[ms][t] = *(const short8*)&Ks[buf][ms * 32 + l5][t * 16 + b5 * 8];

    floatx16 s0, s1;
#pragma unroll
    for (int r = 0; r < 16; r++) { s0[r] = 0.f; s1[r] = 0.f; }
#pragma unroll
    for (int t = 0; t < 4; t++) {
      s0 = __builtin_amdgcn_mfma_f32_32x32x16_bf16(kf[0][t], qf[t], s0, 0, 0, 0);
      s1 = __builtin_amdgcn_mfma_f32_32x32x16_bf16(kf[1][t], qf[t], s1, 0, 0, 0);
    }
    if (__any(mk0 != 0.0f || mk1 != 0.0f)) {
      short8 am0 = {0, 0, 0, 0, 0, 0, 0, 0}, am1 = {0, 0, 0, 0, 0, 0, 0, 0};
      if (b5 == 0) {
        am0[0] = (short)f2bf(1.442695040888963f * mk0);
        am1[0] = (short)f2bf(1.442695040888963f * mk1);
      }
      s0 = __builtin_amdgcn_mfma_f32_32x32x16_bf16(am0, bones, s0, 0, 0, 0);
      s1 = __builtin_amdgcn_mfma_f32_32x32x16_bf16(am1, bones, s1, 0, 0, 0);
    }
    if (it > 0) do_pv(sp0, sp1, pbuf);
    sp0 = s0; sp1 = s1; pbuf = buf;
    buf = (buf == 2) ? 0 : buf + 1;
  }
  do_pv(sp0, sp1, pbuf);

  float inv = 1.0f / Lacc[0];
  int qrow = q0 + l5;
  unsigned short* op = ctx + (size_t)(b * LL + qrow) * 512 + h * 64;
#pragma unroll
  for (int ds = 0; ds < 2; ds++) {
#pragma unroll
    for (int g = 0; g < 4; g++) {
      uint2 w;
      w.x = pack_bf16(O[ds][4 * g] * inv, O[ds][4 * g + 1] * inv);
      w.y = pack_bf16(O[ds][4 * g + 2] * inv, O[ds][4 * g + 3] * inv);
      *(uint2*)(op + ds * 32 + 8 * g + 4 * b5) = w;
    }
  }
}

extern "C" void kernel_launch(void* const* d_in, const int* in_sizes, int n_in,
                              void* d_out, int out_size, void* d_ws, size_t ws_size,
                              hipStream_t stream) {
  const float* x_in = (const float*)d_in[0];
  const float* pcos = (const float*)d_in[1];
  const float* psin = (const float*)d_in[2];
  const float* amask = (const float*)d_in[3];
  const float* Wq = (const float*)d_in[4];
  const float* Wk = (const float*)d_in[5];
  const float* Wv = (const float*)d_in[6];
  const float* Wo = (const float*)d_in[7];
  const float* W1 = (const float*)d_in[8];
  const float* W2 = (const float*)d_in[9];
  const float* ln1w = (const float*)d_in[10];
  const float* ln1b = (const float*)d_in[11];
  const float* ln2w = (const float*)d_in[12];
  const float* ln2b = (const float*)d_in[13];
  const float* lnfw = (const float*)d_in[14];
  const float* lnfb = (const float*)d_in[15];

  const int M = BB * LL;  // 8192
  char* p = (char*)d_ws;
  float* x_ws = (float*)p;                  p += (size_t)M * DD * 4;
  unsigned short* xn = (unsigned short*)p;  p += (size_t)M * DD * 2;
  unsigned short* qkv = (unsigned short*)p; p += (size_t)M * 1536 * 2;
  unsigned short* vtb = (unsigned short*)p; p += (size_t)M * DD * 2;
  unsigned short* cb = (unsigned short*)p;  p += (size_t)M * DD * 2;
  unsigned short* wts = (unsigned short*)p;
  unsigned short* gb = vtb;  // vtb dead after attn; reused for SwiGLU output

  const size_t LW = 786432 + 262144 + 524288 + 262144;
  TJobs jobs;
  for (int i = 0; i < NLAYER; i++) {
    unsigned short* wl = wts + i * LW;
    jobs.j[i * 6 + 0] = {Wq + (size_t)i * 262144, wl + 0, 512, 0};
    jobs.j[i * 6 + 1] = {Wk + (size_t)i * 262144, wl + 262144, 512, 0};
    jobs.j[i * 6 + 2] = {Wv + (size_t)i * 262144, wl + 524288, 512, 0};
    jobs.j[i * 6 + 3] = {Wo + (size_t)i * 262144, wl + 786432, 512, 0};
    jobs.j[i * 6 + 4] = {W1 + (size_t)i * 524288, wl + 1048576, 1024, 1};
    jobs.j[i * 6 + 5] = {W2 + (size_t)i * 262144, wl + 1572864, 512, 0};
  }
  transpose_all_kernel<<<dim3(32, 16, 12), 256, 0, stream>>>(jobs);

  for (int i = 0; i < NLAYER; i++) {
    unsigned short* wl = wts + i * LW;
    const float* xin = (i == 0) ? x_in : x_ws;
    ln_kernel<<<M, 256, 0, stream>>>(xin, ln1w + i * DD, ln1b + i * DD, xn, nullptr);
    gemm128_kernel<<<dim3(12, 64), 256, 0, stream>>>(xn, wl + 0, nullptr, qkv, nullptr, M, 1536, 512, vtb);
    rope_kernel<<<dim3(32, 32), 256, 0, stream>>>(qkv, pcos, psin);
    attn_kernel<<<dim3(LL / 128, HH, BB), 256, 0, stream>>>(qkv, vtb, amask, cb);
    gemm64n_kernel<<<dim3(8, 64), 256, 0, stream>>>(cb, wl + 786432, x_ws, xin, M, 512, 512);
    ln_kernel<<<M, 256, 0, stream>>>(x_ws, ln2w + i * DD, ln2b + i * DD, xn, nullptr);
    gemm_swiglu_kernel<<<dim3(8, 64), 256, 0, stream>>>(xn, wl + 1048576, gb, M, 1024, 512);
    gemm64n_kernel<<<dim3(8, 64), 256, 0, stream>>>(gb, wl + 1572864, x_ws, x_ws, M, 512, 512);
  }
  ln_kernel<<<M, 256, 0, stream>>>(x_ws, lnfw, lnfb, nullptr, (float*)d_out);
}